// Round 9
// baseline (17.174 us; speedup 1.0000x reference)
//
#include <hip/hip_runtime.h>
#include <math.h>

using bf16x8 = __attribute__((ext_vector_type(8))) short;   // 8 bf16 in 4 VGPRs
using f32x16 = __attribute__((ext_vector_type(16))) float;  // 32x32 MFMA acc

static __device__ __forceinline__ unsigned cvt_pk_bf16(float lo, float hi) {
    unsigned r;
    asm("v_cvt_pk_bf16_f32 %0, %1, %2" : "=v"(r) : "v"(lo), "v"(hi));
    return r;
}

#define REV_HALF 0.07957747154594767f  // 1/(4*pi): theta -> revolutions of theta/2

// One WAVE = one image; no LDS, no __syncthreads. 256-thread blocks = 4 images.
// Per round r=0..3: lane builds psi of patch r*64+lane (R7-verified bf16 halves);
// tiles T (2 for r<3, 1 for r=3): shfl B-frag -> mfma_f32_32x32x16_bf16 with
// A=[U_re;U_im] (K=16 exact) -> P=Re^2+Im^2 -> 8-pt Walsh + xor32 -> z-quad in
// ALL lanes (R7-verified) -> head partial acc[5] per half (classes hi*5..+4).
// End: 25+5 shfl reduce/exchange, in-register softmax, lanes 0..9 store.
__global__ __launch_bounds__(256) void quanv_wave(
    const float* __restrict__ x,      // [N,1,28,28]
    const float* __restrict__ U_re,   // [16,16]
    const float* __restrict__ U_im,   // [16,16]
    const float* __restrict__ W,      // [10,784]
    const float* __restrict__ bias,   // [10]
    float* __restrict__ out,          // [N,10]
    int n_img)
{
    const int tid  = threadIdx.x;
    const int wv   = tid >> 6;
    const int lane = tid & 63;
    const int l31  = lane & 31;
    const int hi   = lane >> 5;       // k-half / j2 bit / class-half
    const int img  = blockIdx.x * 4 + wv;
    if (img >= n_img) return;

    // ---- A fragment: stacked 32x16 [U_re; U_im]; row=lane&31, k=hi*8+i ----
    const float* Urow = (l31 < 16) ? (U_re + l31 * 16) : (U_im + (l31 - 16) * 16);
    const float4 uf0 = *(const float4*)(Urow + hi * 8);
    const float4 uf1 = *(const float4*)(Urow + hi * 8 + 4);
    union { unsigned u[4]; bf16x8 v; } ua;
    ua.u[0] = cvt_pk_bf16(uf0.x, uf0.y);
    ua.u[1] = cvt_pk_bf16(uf0.z, uf0.w);
    ua.u[2] = cvt_pk_bf16(uf1.x, uf1.y);
    ua.u[3] = cvt_pk_bf16(uf1.z, uf1.w);

    const float* xim = x + (size_t)img * 784;
    const int cs = hi * 5;            // this half's first class
    float acc0 = 0.f, acc1 = 0.f, acc2 = 0.f, acc3 = 0.f, acc4 = 0.f;

    f32x16 zacc;
    #pragma unroll
    for (int i = 0; i < 16; ++i) zacc[i] = 0.f;

    #pragma unroll
    for (int r = 0; r < 4; ++r) {
        // ---- psi for this lane's round-r patch (clamped) ----
        const int pown = r * 64 + lane;
        const int pc   = (pown < 196) ? pown : 195;
        const int prw  = pc / 14;
        const int pcl  = pc - prw * 14;
        const float* xi = xim + prw * 56 + pcl * 2;
        const float2 t0 = *(const float2*)xi;
        const float2 t1 = *(const float2*)(xi + 28);
        const float r0 = t0.x * REV_HALF, r1 = t0.y * REV_HALF;
        const float r2 = t1.x * REV_HALF, r3 = t1.y * REV_HALF;
        const float s0 = __builtin_amdgcn_sinf(r0), c0 = __builtin_amdgcn_cosf(r0);
        const float s1 = __builtin_amdgcn_sinf(r1), c1 = __builtin_amdgcn_cosf(r1);
        const float s2 = __builtin_amdgcn_sinf(r2), c2 = __builtin_amdgcn_cosf(r2);
        const float s3 = __builtin_amdgcn_sinf(r3), c3 = __builtin_amdgcn_cosf(r3);
        const float a0 = c0 * c1, a1 = c0 * s1, a2 = s0 * c1, a3 = s0 * s1;
        const float b0 = c2 * c3, b1 = c2 * s3, b2 = s2 * c3, b3 = s2 * s3;

        unsigned pL[4], pH[4];
        pL[0] = cvt_pk_bf16(a0 * b0, a0 * b1); pL[1] = cvt_pk_bf16(a0 * b2, a0 * b3);
        pL[2] = cvt_pk_bf16(a1 * b0, a1 * b1); pL[3] = cvt_pk_bf16(a1 * b2, a1 * b3);
        pH[0] = cvt_pk_bf16(a2 * b0, a2 * b1); pH[1] = cvt_pk_bf16(a2 * b2, a2 * b3);
        pH[2] = cvt_pk_bf16(a3 * b0, a3 * b1); pH[3] = cvt_pk_bf16(a3 * b2, a3 * b3);

        const int ntile = (r < 3) ? 2 : 1;
        #pragma unroll
        for (int T = 0; T < 2; ++T) {
            if (T < ntile) {
                // ---- B fragment (R7-verified shfl redistribution) ----
                union { unsigned u[4]; bf16x8 v; } pb;
                #pragma unroll
                for (int c = 0; c < 4; ++c) {
                    if (T == 0) {
                        const unsigned sw = (unsigned)__shfl_xor((int)pH[c], 32, 64);
                        pb.u[c] = hi ? sw : pL[c];
                    } else {
                        const unsigned sw = (unsigned)__shfl_xor((int)pL[c], 32, 64);
                        pb.u[c] = hi ? pH[c] : sw;
                    }
                }

                const f32x16 d = __builtin_amdgcn_mfma_f32_32x32x16_bf16(ua.v, pb.v, zacc, 0, 0, 0);

                float P[8];
                #pragma unroll
                for (int q = 0; q < 8; ++q) P[q] = fmaf(d[q], d[q], d[q + 8] * d[q + 8]);

                // 8-point Walsh over in-register j bits {j0,j1,j3}; j2 = hi.
                const float u0 = P[0] + P[1], u1 = P[0] - P[1];
                const float u2 = P[2] + P[3], u3 = P[2] - P[3];
                const float v0 = P[4] + P[5], v1 = P[4] - P[5];
                const float v2 = P[6] + P[7], v3 = P[6] - P[7];
                const float tpp0 = u0 + u2, tb1_0 = u0 - u2, tb0_0 = u1 + u3;
                const float tpp1 = v0 + v2, tb1_1 = v0 - v2, tb0_1 = v1 + v3;
                const float S   = tpp0 + tpp1;
                const float z0p = tpp0 - tpp1;
                const float z2p = tb1_0 + tb1_1;
                const float z3p = tb0_0 + tb0_1;
                const float Sx = __shfl_xor(S, 32, 64);
                float z0 = z0p + __shfl_xor(z0p, 32, 64);
                float z2 = z2p + __shfl_xor(z2p, 32, 64);
                float z3 = z3p + __shfl_xor(z3p, 32, 64);
                float z1 = hi ? (Sx - S) : (S - Sx);

                // ---- fused head partial: patch p = r*64 + T*32 + l31 ----
                int p = r * 64 + T * 32 + l31;
                if (p >= 196) { z0 = 0.f; z1 = 0.f; z2 = 0.f; z3 = 0.f; p = 195; }
                const float* wb = W + (size_t)p * 4;
                const float4 w0 = *(const float4*)(wb + (cs + 0) * 784);
                const float4 w1 = *(const float4*)(wb + (cs + 1) * 784);
                const float4 w2 = *(const float4*)(wb + (cs + 2) * 784);
                const float4 w3 = *(const float4*)(wb + (cs + 3) * 784);
                const float4 w4 = *(const float4*)(wb + (cs + 4) * 784);
                acc0 = fmaf(w0.x, z0, fmaf(w0.y, z1, fmaf(w0.z, z2, fmaf(w0.w, z3, acc0))));
                acc1 = fmaf(w1.x, z0, fmaf(w1.y, z1, fmaf(w1.z, z2, fmaf(w1.w, z3, acc1))));
                acc2 = fmaf(w2.x, z0, fmaf(w2.y, z1, fmaf(w2.z, z2, fmaf(w2.w, z3, acc2))));
                acc3 = fmaf(w3.x, z0, fmaf(w3.y, z1, fmaf(w3.z, z2, fmaf(w3.w, z3, acc3))));
                acc4 = fmaf(w4.x, z0, fmaf(w4.y, z1, fmaf(w4.z, z2, fmaf(w4.w, z3, acc4))));
            }
        }
    }

    // ---- butterfly reduce over the 32 lanes of each half ----
    #pragma unroll
    for (int off = 16; off; off >>= 1) {
        acc0 += __shfl_xor(acc0, off, 64);
        acc1 += __shfl_xor(acc1, off, 64);
        acc2 += __shfl_xor(acc2, off, 64);
        acc3 += __shfl_xor(acc3, off, 64);
        acc4 += __shfl_xor(acc4, off, 64);
    }
    // ---- exchange halves: oth = other half's 5 logits ----
    const float o0 = __shfl_xor(acc0, 32, 64);
    const float o1 = __shfl_xor(acc1, 32, 64);
    const float o2 = __shfl_xor(acc2, 32, 64);
    const float o3 = __shfl_xor(acc3, 32, 64);
    const float o4 = __shfl_xor(acc4, 32, 64);
    // classes 0..4 from hi=0 half, 5..9 from hi=1 half
    const float l0 = (hi ? o0 : acc0) + bias[0];
    const float l1 = (hi ? o1 : acc1) + bias[1];
    const float l2 = (hi ? o2 : acc2) + bias[2];
    const float l3 = (hi ? o3 : acc3) + bias[3];
    const float l4 = (hi ? o4 : acc4) + bias[4];
    const float l5 = (hi ? acc0 : o0) + bias[5];
    const float l6 = (hi ? acc1 : o1) + bias[6];
    const float l7 = (hi ? acc2 : o2) + bias[7];
    const float l8 = (hi ? acc3 : o3) + bias[8];
    const float l9 = (hi ? acc4 : o4) + bias[9];

    // ---- in-register log_softmax (all lanes redundantly) ----
    float m = fmaxf(l0, l1);
    m = fmaxf(m, l2); m = fmaxf(m, l3); m = fmaxf(m, l4);
    m = fmaxf(m, l5); m = fmaxf(m, l6); m = fmaxf(m, l7);
    m = fmaxf(m, l8); m = fmaxf(m, l9);
    const float ssum = __expf(l0 - m) + __expf(l1 - m) + __expf(l2 - m) +
                       __expf(l3 - m) + __expf(l4 - m) + __expf(l5 - m) +
                       __expf(l6 - m) + __expf(l7 - m) + __expf(l8 - m) +
                       __expf(l9 - m);
    const float lse = m + __logf(ssum);

    // lane k (0..9) stores class k: static-index select chain
    float myv = l0;
    myv = (lane == 1) ? l1 : myv;
    myv = (lane == 2) ? l2 : myv;
    myv = (lane == 3) ? l3 : myv;
    myv = (lane == 4) ? l4 : myv;
    myv = (lane == 5) ? l5 : myv;
    myv = (lane == 6) ? l6 : myv;
    myv = (lane == 7) ? l7 : myv;
    myv = (lane == 8) ? l8 : myv;
    myv = (lane == 9) ? l9 : myv;
    if (lane < 10) out[(size_t)img * 10 + lane] = myv - lse;
}

extern "C" void kernel_launch(void* const* d_in, const int* in_sizes, int n_in,
                              void* d_out, int out_size, void* d_ws, size_t ws_size,
                              hipStream_t stream) {
    const float* x    = (const float*)d_in[0];
    const float* U_re = (const float*)d_in[1];
    const float* U_im = (const float*)d_in[2];
    const float* W    = (const float*)d_in[3];
    const float* bias = (const float*)d_in[4];
    float* out = (float*)d_out;
    const int n = in_sizes[0] / 784;  // 4096 images
    const int nblk = (n + 3) / 4;     // 4 images (waves) per 256-thread block
    quanv_wave<<<nblk, 256, 0, stream>>>(x, U_re, U_im, W, bias, out, n);
}